// Round 1
// baseline (6495.657 us; speedup 1.0000x reference)
//
#include <hip/hip_runtime.h>
#include <math.h>

#define NN 100000
#define FIN 27
#define EMB 64
#define HH 128
#define LAYERS 4
#define GG 512

__device__ __forceinline__ float sigmf(float x) { return 1.0f / (1.0f + expf(-x)); }

// x1 = sigmoid(x @ lin0_w); h = pad(x1) to 128. One wave per node, lane = emb channel.
__global__ void lin0_kernel(const float* __restrict__ x, const float* __restrict__ w,
                            float* __restrict__ x1_out, float* __restrict__ h, int n) {
    int wave = (int)((blockIdx.x * blockDim.x + threadIdx.x) >> 6);
    int lane = threadIdx.x & 63;
    if (wave >= n) return;
    const float* xr = x + (size_t)wave * FIN;
    float acc = 0.0f;
#pragma unroll
    for (int k = 0; k < FIN; ++k) acc += xr[k] * w[k * EMB + lane];
    float v = sigmf(acc);
    x1_out[(size_t)wave * EMB + lane] = v;
    size_t base = (size_t)wave * HH;
    h[base + lane] = v;
    h[base + 64 + lane] = 0.0f;
}

__global__ void hist_kernel(const int* __restrict__ dst, int* __restrict__ deg, int e) {
    int i = blockIdx.x * blockDim.x + threadIdx.x;
    if (i < e) atomicAdd(&deg[dst[i]], 1);
}

// Single-block exclusive scan: rowptr[i+1] = sum(deg[0..i]); cursor[i] = rowptr[i].
__global__ void scan_kernel(const int* __restrict__ deg, int* __restrict__ rowptr,
                            int* __restrict__ cursor, int n) {
    __shared__ int part[1024];
    int t = threadIdx.x;
    int chunk = (n + 1023) / 1024;
    int lo = t * chunk;
    int hi = lo + chunk; if (hi > n) hi = n; if (lo > n) lo = n;
    int s = 0;
    for (int i = lo; i < hi; ++i) s += deg[i];
    part[t] = s;
    __syncthreads();
    for (int off = 1; off < 1024; off <<= 1) {
        int v = (t >= off) ? part[t - off] : 0;
        __syncthreads();
        part[t] += v;
        __syncthreads();
    }
    int run = (t == 0) ? 0 : part[t - 1];
    if (t == 0) rowptr[0] = 0;
    for (int i = lo; i < hi; ++i) {
        cursor[i] = run;
        run += deg[i];
        rowptr[i + 1] = run;
    }
}

__global__ void scatter_kernel(const int* __restrict__ src, const int* __restrict__ dst,
                               int* __restrict__ cursor, int* __restrict__ col, int e) {
    int i = blockIdx.x * blockDim.x + threadIdx.x;
    if (i < e) {
        int pos = atomicAdd(&cursor[dst[i]], 1);
        col[pos] = src[i];
    }
}

// w: [3H][H] row-major -> wt: [H][3H]  (wt[k*384+r] = w[r*128+k])
__global__ void transpose_w(const float* __restrict__ w, float* __restrict__ wt) {
    int i = blockIdx.x * blockDim.x + threadIdx.x;
    if (i < 3 * HH * HH) {
        int k = i / (3 * HH);
        int r = i % (3 * HH);
        wt[i] = w[r * HH + k];
    }
}

// agg[v] = sum over in-edges of h[src]. One wave per node; lanes = channels (2 per lane).
__global__ void aggregate_kernel(const float* __restrict__ h, const int* __restrict__ rowptr,
                                 const int* __restrict__ col, float* __restrict__ agg, int n) {
    int wave = (int)((blockIdx.x * blockDim.x + threadIdx.x) >> 6);
    int lane = threadIdx.x & 63;
    if (wave >= n) return;
    int r0 = rowptr[wave], r1 = rowptr[wave + 1];
    float lo = 0.0f, hi = 0.0f;
    for (int j = r0; j < r1; ++j) {
        int s = col[j];
        const float* hr = h + (size_t)s * HH;
        lo += hr[lane];
        hi += hr[64 + lane];
    }
    size_t base = (size_t)wave * HH;
    agg[base + lane] = lo;
    agg[base + 64 + lane] = hi;
}

// Fused per-node GRU layer:  m = agg @ W;  gi = m@w_ih^T+b_ih; gh = h@w_hh^T+b_hh; gates.
// h_out may alias agg_in (each wave reads its agg row fully before writing h_out row).
__global__ void gru_kernel(const float* agg_in, const float* h_in,
                           const float* __restrict__ W, const float* __restrict__ wihT,
                           const float* __restrict__ whhT, const float* __restrict__ b_ih,
                           const float* __restrict__ b_hh, float* h_out, int n) {
    int wave = (int)((blockIdx.x * blockDim.x + threadIdx.x) >> 6);
    int lane = threadIdx.x & 63;
    if (wave >= n) return;
    size_t base = (size_t)wave * HH;
    float a_lo = agg_in[base + lane], a_hi = agg_in[base + 64 + lane];
    float h_lo = h_in[base + lane], h_hi = h_in[base + 64 + lane];

    // m = agg @ W   (m_lo = col lane, m_hi = col lane+64)
    float m_lo = 0.0f, m_hi = 0.0f;
    for (int k = 0; k < HH; ++k) {
        float ak = (k < 64) ? __shfl(a_lo, k, 64) : __shfl(a_hi, k - 64, 64);
        const float* wr = W + k * HH + lane;
        m_lo += ak * wr[0];
        m_hi += ak * wr[64];
    }

    // gates: r indices = lane + 64*rr, rr=0..5 covering [i_r | i_z | i_n] halves
    float g1[6] = {0, 0, 0, 0, 0, 0};
    float g2[6] = {0, 0, 0, 0, 0, 0};
    for (int k = 0; k < HH; ++k) {
        float mk = (k < 64) ? __shfl(m_lo, k, 64) : __shfl(m_hi, k - 64, 64);
        float hk = (k < 64) ? __shfl(h_lo, k, 64) : __shfl(h_hi, k - 64, 64);
        const float* wi = wihT + k * (3 * HH) + lane;
        const float* wh = whhT + k * (3 * HH) + lane;
#pragma unroll
        for (int rr = 0; rr < 6; ++rr) {
            g1[rr] += mk * wi[64 * rr];
            g2[rr] += hk * wh[64 * rr];
        }
    }
#pragma unroll
    for (int rr = 0; rr < 6; ++rr) {
        g1[rr] += b_ih[lane + 64 * rr];
        g2[rr] += b_hh[lane + 64 * rr];
    }
    float r_lo = sigmf(g1[0] + g2[0]);
    float r_hi = sigmf(g1[1] + g2[1]);
    float z_lo = sigmf(g1[2] + g2[2]);
    float z_hi = sigmf(g1[3] + g2[3]);
    float n_lo = tanhf(g1[4] + r_lo * g2[4]);
    float n_hi = tanhf(g1[5] + r_hi * g2[5]);
    h_out[base + lane] = (1.0f - z_lo) * n_lo + z_lo * h_lo;
    h_out[base + 64 + lane] = (1.0f - z_hi) * n_hi + z_hi * h_hi;
}

// mu/sigma per node + per-graph atomic sums. One wave per node.
__global__ void readout_kernel(const float* __restrict__ h, const float* __restrict__ w1,
                               const float* __restrict__ b1, const float* __restrict__ w2,
                               const float* __restrict__ b2, const int* __restrict__ batch,
                               float* __restrict__ out_mu, float* __restrict__ out_sg,
                               float* __restrict__ gsum, int n) {
    int wave = (int)((blockIdx.x * blockDim.x + threadIdx.x) >> 6);
    int lane = threadIdx.x & 63;
    if (wave >= n) return;
    size_t base = (size_t)wave * HH;
    float xlo = fmaxf(h[base + lane], 0.0f);
    float xhi = fmaxf(h[base + 64 + lane], 0.0f);
    float a1 = xlo * w1[lane] + xhi * w1[64 + lane];
    float a2 = xlo * w2[lane] + xhi * w2[64 + lane];
#pragma unroll
    for (int off = 32; off > 0; off >>= 1) {
        a1 += __shfl_down(a1, off, 64);
        a2 += __shfl_down(a2, off, 64);
    }
    if (lane == 0) {
        float mu = a1 + b1[0];
        float x2 = a2 + b2[0];
        float sg = (x2 > 20.0f) ? x2 : log1pf(expf(x2));
        out_mu[wave] = mu;
        out_sg[wave] = sg;
        int b = batch[wave];
        atomicAdd(&gsum[b], mu);
        atomicAdd(&gsum[GG + b], sg);
    }
}

__global__ void correction_kernel(const float* __restrict__ out_mu, const float* __restrict__ out_sg,
                                  const float* __restrict__ gsum, const int* __restrict__ batch,
                                  float* __restrict__ out_muc, int n) {
    int i = blockIdx.x * blockDim.x + threadIdx.x;
    if (i < n) {
        int b = batch[i];
        out_muc[i] = out_mu[i] - gsum[b] * (out_sg[i] / gsum[GG + b]);
    }
}

extern "C" void kernel_launch(void* const* d_in, const int* in_sizes, int n_in,
                              void* d_out, int out_size, void* d_ws, size_t ws_size,
                              hipStream_t stream) {
    const float* x      = (const float*)d_in[0];
    const int*   ei     = (const int*)d_in[1];
    const int*   batch  = (const int*)d_in[2];
    const float* lin0_w = (const float*)d_in[3];
    const float* ggc    = (const float*)d_in[4];
    const float* w_ih   = (const float*)d_in[5];
    const float* w_hh   = (const float*)d_in[6];
    const float* b_ih   = (const float*)d_in[7];
    const float* b_hh   = (const float*)d_in[8];
    const float* l1w    = (const float*)d_in[9];
    const float* l1b    = (const float*)d_in[10];
    const float* l2w    = (const float*)d_in[11];
    const float* l2b    = (const float*)d_in[12];

    int n = in_sizes[0] / FIN;   // 100000
    int e = in_sizes[1] / 2;     // 1600000
    const int* src = ei;
    const int* dstp = ei + e;

    float* out = (float*)d_out;
    float* out_muc = out;                              // [n]
    float* out_x1  = out + n;                          // [n*64]
    float* out_sg  = out + n + (size_t)n * EMB;        // [n]
    float* out_mu  = out_sg + n;                       // [n] (uncorrected)

    // workspace layout
    float* hA    = (float*)d_ws;                       // n*128
    float* hB    = hA + (size_t)n * HH;                // n*128
    float* wihT  = hB + (size_t)n * HH;                // 128*384
    float* whhT  = wihT + 3 * HH * HH;                 // 128*384
    float* gsum  = whhT + 3 * HH * HH;                 // 2*512
    int*   deg    = (int*)(gsum + 2 * GG);             // n
    int*   rowptr = deg + n;                           // n+1
    int*   cursor = rowptr + n + 1;                    // n
    int*   col    = cursor + n;                        // e

    hipMemsetAsync(deg, 0, (size_t)n * sizeof(int), stream);
    hipMemsetAsync(gsum, 0, 2 * GG * sizeof(float), stream);

    int wave_blocks = (n * 64 + 255) / 256;
    lin0_kernel<<<wave_blocks, 256, 0, stream>>>(x, lin0_w, out_x1, hA, n);
    hist_kernel<<<(e + 255) / 256, 256, 0, stream>>>(dstp, deg, e);
    scan_kernel<<<1, 1024, 0, stream>>>(deg, rowptr, cursor, n);
    scatter_kernel<<<(e + 255) / 256, 256, 0, stream>>>(src, dstp, cursor, col, e);
    transpose_w<<<(3 * HH * HH + 255) / 256, 256, 0, stream>>>(w_ih, wihT);
    transpose_w<<<(3 * HH * HH + 255) / 256, 256, 0, stream>>>(w_hh, whhT);

    float* cur = hA;
    float* scr = hB;
    for (int l = 0; l < LAYERS; ++l) {
        aggregate_kernel<<<wave_blocks, 256, 0, stream>>>(cur, rowptr, col, scr, n);
        gru_kernel<<<wave_blocks, 256, 0, stream>>>(scr, cur, ggc + (size_t)l * HH * HH,
                                                    wihT, whhT, b_ih, b_hh, scr, n);
        float* t = cur; cur = scr; scr = t;
    }

    readout_kernel<<<wave_blocks, 256, 0, stream>>>(cur, l1w, l1b, l2w, l2b, batch,
                                                    out_mu, out_sg, gsum, n);
    correction_kernel<<<(n + 255) / 256, 256, 0, stream>>>(out_mu, out_sg, gsum, batch,
                                                           out_muc, n);
}

// Round 2
// 1794.234 us; speedup vs baseline: 3.6203x; 3.6203x over previous
//
#include <hip/hip_runtime.h>
#include <math.h>

#define NN 100000
#define FIN 27
#define EMB 64
#define HH 128
#define LAYERS 4
#define GG 512

typedef __attribute__((ext_vector_type(8))) short short8;
typedef __attribute__((ext_vector_type(4))) float floatx4;

__device__ __forceinline__ float sigmf(float x) { return 1.0f / (1.0f + expf(-x)); }

__device__ __forceinline__ unsigned short f2bf(float f) {
    unsigned int u = __float_as_uint(f);
    u += 0x7FFFu + ((u >> 16) & 1u);
    return (unsigned short)(u >> 16);
}

// x1 = sigmoid(x @ lin0_w); h = pad(x1) to 128 (fp32 + bf16 mirror).
__global__ void lin0_kernel(const float* __restrict__ x, const float* __restrict__ w,
                            float* __restrict__ x1_out, float* __restrict__ hf,
                            unsigned short* __restrict__ hbf, int n) {
    int wave = (int)((blockIdx.x * blockDim.x + threadIdx.x) >> 6);
    int lane = threadIdx.x & 63;
    if (wave >= n) return;
    const float* xr = x + (size_t)wave * FIN;
    float acc = 0.0f;
#pragma unroll
    for (int k = 0; k < FIN; ++k) acc += xr[k] * w[k * EMB + lane];
    float v = sigmf(acc);
    x1_out[(size_t)wave * EMB + lane] = v;
    size_t base = (size_t)wave * HH;
    hf[base + lane] = v;
    hf[base + 64 + lane] = 0.0f;
    hbf[base + lane] = f2bf(v);
    hbf[base + 64 + lane] = 0;
}

__global__ void hist_kernel(const int* __restrict__ dst, int* __restrict__ deg, int e) {
    int i = blockIdx.x * blockDim.x + threadIdx.x;
    if (i < e) atomicAdd(&deg[dst[i]], 1);
}

__global__ void scan_kernel(const int* __restrict__ deg, int* __restrict__ rowptr,
                            int* __restrict__ cursor, int n) {
    __shared__ int part[1024];
    int t = threadIdx.x;
    int chunk = (n + 1023) / 1024;
    int lo = t * chunk;
    int hi = lo + chunk; if (hi > n) hi = n; if (lo > n) lo = n;
    int s = 0;
    for (int i = lo; i < hi; ++i) s += deg[i];
    part[t] = s;
    __syncthreads();
    for (int off = 1; off < 1024; off <<= 1) {
        int v = (t >= off) ? part[t - off] : 0;
        __syncthreads();
        part[t] += v;
        __syncthreads();
    }
    int run = (t == 0) ? 0 : part[t - 1];
    if (t == 0) rowptr[0] = 0;
    for (int i = lo; i < hi; ++i) {
        cursor[i] = run;
        run += deg[i];
        rowptr[i + 1] = run;
    }
}

__global__ void scatter_kernel(const int* __restrict__ src, const int* __restrict__ dst,
                               int* __restrict__ cursor, int* __restrict__ col, int e) {
    int i = blockIdx.x * blockDim.x + threadIdx.x;
    if (i < e) {
        int pos = atomicAdd(&cursor[dst[i]], 1);
        col[pos] = src[i];
    }
}

// Pack whh^T into MFMA B-fragment order:
// whhp[((kt*24+ct)*64+lane)*8 + j] = w_hh[col*128 + k], col=ct*16+(lane&15), k=kt*32+(lane>>4)*8+j
__global__ void pack_whh(const float* __restrict__ w_hh, unsigned short* __restrict__ whhp) {
    int id = blockIdx.x * blockDim.x + threadIdx.x;
    if (id >= 4 * 24 * 64 * 8) return;
    int j = id & 7;
    int lane = (id >> 3) & 63;
    int ctkt = id >> 9;
    int ct = ctkt % 24;
    int kt = ctkt / 24;
    int k = kt * 32 + (lane >> 4) * 8 + j;
    int col = ct * 16 + (lane & 15);
    whhp[id] = f2bf(w_hh[col * HH + k]);
}

// Wf[l] = ggc[l] @ w_ih^T, packed in MFMA B-fragment order (bf16).
// Wfp[l*49152 + rem] where rem = ((kt*24+ct)*64+lane)*8 + j; value = sum_q ggc[l][k][q]*w_ih[col][q]
__global__ void pack_wf(const float* __restrict__ ggc, const float* __restrict__ w_ih,
                        unsigned short* __restrict__ Wfp) {
    int id = blockIdx.x * blockDim.x + threadIdx.x;
    if (id >= LAYERS * 4 * 24 * 64 * 8) return;
    int l = id / 49152;
    int rem = id % 49152;
    int j = rem & 7;
    int lane = (rem >> 3) & 63;
    int ctkt = rem >> 9;
    int ct = ctkt % 24;
    int kt = ctkt / 24;
    int k = kt * 32 + (lane >> 4) * 8 + j;
    int col = ct * 16 + (lane & 15);
    const float* gr = ggc + ((size_t)l * HH + k) * HH;
    const float* wr = w_ih + (size_t)col * HH;
    float acc = 0.0f;
#pragma unroll 8
    for (int q = 0; q < HH; ++q) acc += gr[q] * wr[q];
    Wfp[id] = f2bf(acc);
}

// agg[v] = sum over in-edges of h_bf16[src]. Wave per node; lane = 2 channels (one uint).
__global__ void aggregate_kernel(const unsigned int* __restrict__ hbf2, const int* __restrict__ rowptr,
                                 const int* __restrict__ col, unsigned int* __restrict__ agg2, int n) {
    int wave = (int)((blockIdx.x * blockDim.x + threadIdx.x) >> 6);
    int lane = threadIdx.x & 63;
    if (wave >= n) return;
    int r0 = rowptr[wave], r1 = rowptr[wave + 1];
    float a0 = 0.0f, a1 = 0.0f;
    for (int j = r0; j < r1; ++j) {
        int s = col[j];
        unsigned int v = hbf2[(size_t)s * 64 + lane];
        a0 += __uint_as_float(v << 16);
        a1 += __uint_as_float(v & 0xFFFF0000u);
    }
    unsigned int lo = f2bf(a0);
    unsigned int hi = f2bf(a1);
    agg2[(size_t)wave * 64 + lane] = lo | (hi << 16);
}

// Fused GEMM + GRU layer. Block = 256 thr (4 waves) = 32 nodes. Wave w owns channels [32w,32w+32).
// gi = agg @ Wf[l] (+b_ih), gh = h @ whh^T (+b_hh), gates, h' written in place (fp32 + bf16).
__global__ void gru_mfma_kernel(const unsigned short* __restrict__ agg,
                                unsigned short* __restrict__ hbf,
                                float* __restrict__ hf,
                                const unsigned short* __restrict__ Wfp,
                                const unsigned short* __restrict__ whhp,
                                const float* __restrict__ b_ih, const float* __restrict__ b_hh,
                                int n) {
    int wave = threadIdx.x >> 6;
    int lane = threadIdx.x & 63;
    int quad = lane >> 4;
    int l15 = lane & 15;
    int M0 = blockIdx.x * 32;
    if (M0 >= n) return;

    floatx4 acc_gi[3][2][2];  // [gate r/z/n][coltile t][rowtile r]
    floatx4 acc_gh[3][2][2];
#pragma unroll
    for (int g = 0; g < 3; ++g)
#pragma unroll
        for (int t = 0; t < 2; ++t)
#pragma unroll
            for (int r = 0; r < 2; ++r) {
                acc_gi[g][t][r] = (floatx4)0.0f;
                acc_gh[g][t][r] = (floatx4)0.0f;
            }

    for (int kt = 0; kt < 4; ++kt) {
        int kbase = kt * 32 + quad * 8;
        short8 a_a[2], a_h[2];
#pragma unroll
        for (int r = 0; r < 2; ++r) {
            size_t arow = (size_t)(M0 + 16 * r + l15) * HH + kbase;
            a_a[r] = *(const short8*)(agg + arow);
            a_h[r] = *(const short8*)(hbf + arow);
        }
#pragma unroll
        for (int g = 0; g < 3; ++g)
#pragma unroll
            for (int t = 0; t < 2; ++t) {
                int ct = g * 8 + wave * 2 + t;
                size_t boff = ((size_t)(kt * 24 + ct) * 64 + lane) * 8;
                short8 bi = *(const short8*)(Wfp + boff);
                short8 bh = *(const short8*)(whhp + boff);
#pragma unroll
                for (int r = 0; r < 2; ++r) {
                    acc_gi[g][t][r] = __builtin_amdgcn_mfma_f32_16x16x32_bf16(
                        a_a[r], bi, acc_gi[g][t][r], 0, 0, 0);
                    acc_gh[g][t][r] = __builtin_amdgcn_mfma_f32_16x16x32_bf16(
                        a_h[r], bh, acc_gh[g][t][r], 0, 0, 0);
                }
            }
    }

    __syncthreads();  // all waves' A-reads done before any in-place h writes

#pragma unroll
    for (int t = 0; t < 2; ++t) {
        int c = wave * 32 + 16 * t + l15;
        float bir = b_ih[c], biz = b_ih[128 + c], bin_ = b_ih[256 + c];
        float bhr = b_hh[c], bhz = b_hh[128 + c], bhn = b_hh[256 + c];
#pragma unroll
        for (int r = 0; r < 2; ++r) {
#pragma unroll
            for (int j = 0; j < 4; ++j) {
                int node = M0 + 16 * r + quad * 4 + j;
                size_t idx = (size_t)node * HH + c;
                float gir = acc_gi[0][t][r][j] + bir;
                float ghr = acc_gh[0][t][r][j] + bhr;
                float giz = acc_gi[1][t][r][j] + biz;
                float ghz = acc_gh[1][t][r][j] + bhz;
                float gin = acc_gi[2][t][r][j] + bin_;
                float ghn = acc_gh[2][t][r][j] + bhn;
                float rr = sigmf(gir + ghr);
                float zz = sigmf(giz + ghz);
                float nn = tanhf(gin + rr * ghn);
                float hp = hf[idx];
                float hn = (1.0f - zz) * nn + zz * hp;
                hf[idx] = hn;
                hbf[idx] = f2bf(hn);
            }
        }
    }
}

__global__ void readout_kernel(const float* __restrict__ h, const float* __restrict__ w1,
                               const float* __restrict__ b1, const float* __restrict__ w2,
                               const float* __restrict__ b2, const int* __restrict__ batch,
                               float* __restrict__ out_mu, float* __restrict__ out_sg,
                               float* __restrict__ gsum, int n) {
    int wave = (int)((blockIdx.x * blockDim.x + threadIdx.x) >> 6);
    int lane = threadIdx.x & 63;
    if (wave >= n) return;
    size_t base = (size_t)wave * HH;
    float xlo = fmaxf(h[base + lane], 0.0f);
    float xhi = fmaxf(h[base + 64 + lane], 0.0f);
    float a1 = xlo * w1[lane] + xhi * w1[64 + lane];
    float a2 = xlo * w2[lane] + xhi * w2[64 + lane];
#pragma unroll
    for (int off = 32; off > 0; off >>= 1) {
        a1 += __shfl_down(a1, off, 64);
        a2 += __shfl_down(a2, off, 64);
    }
    if (lane == 0) {
        float mu = a1 + b1[0];
        float x2 = a2 + b2[0];
        float sg = (x2 > 20.0f) ? x2 : log1pf(expf(x2));
        out_mu[wave] = mu;
        out_sg[wave] = sg;
        int b = batch[wave];
        atomicAdd(&gsum[b], mu);
        atomicAdd(&gsum[GG + b], sg);
    }
}

__global__ void correction_kernel(const float* __restrict__ out_mu, const float* __restrict__ out_sg,
                                  const float* __restrict__ gsum, const int* __restrict__ batch,
                                  float* __restrict__ out_muc, int n) {
    int i = blockIdx.x * blockDim.x + threadIdx.x;
    if (i < n) {
        int b = batch[i];
        out_muc[i] = out_mu[i] - gsum[b] * (out_sg[i] / gsum[GG + b]);
    }
}

extern "C" void kernel_launch(void* const* d_in, const int* in_sizes, int n_in,
                              void* d_out, int out_size, void* d_ws, size_t ws_size,
                              hipStream_t stream) {
    const float* x      = (const float*)d_in[0];
    const int*   ei     = (const int*)d_in[1];
    const int*   batch  = (const int*)d_in[2];
    const float* lin0_w = (const float*)d_in[3];
    const float* ggc    = (const float*)d_in[4];
    const float* w_ih   = (const float*)d_in[5];
    const float* w_hh   = (const float*)d_in[6];
    const float* b_ih   = (const float*)d_in[7];
    const float* b_hh   = (const float*)d_in[8];
    const float* l1w    = (const float*)d_in[9];
    const float* l1b    = (const float*)d_in[10];
    const float* l2w    = (const float*)d_in[11];
    const float* l2b    = (const float*)d_in[12];

    int n = in_sizes[0] / FIN;   // 100000
    int e = in_sizes[1] / 2;     // 1600000
    const int* src = ei;
    const int* dstp = ei + e;

    float* out = (float*)d_out;
    float* out_muc = out;                              // [n]
    float* out_x1  = out + n;                          // [n*64]
    float* out_sg  = out + n + (size_t)n * EMB;        // [n]
    float* out_mu  = out_sg + n;                       // [n]

    // workspace layout (all 16B aligned)
    float*          hf   = (float*)d_ws;                               // n*128 fp32
    unsigned short* hbf  = (unsigned short*)(hf + (size_t)n * HH);     // n*128 bf16
    unsigned short* agg  = hbf + (size_t)n * HH;                       // n*128 bf16
    unsigned short* Wfp  = agg + (size_t)n * HH;                       // 4*49152 bf16
    unsigned short* whhp = Wfp + (size_t)LAYERS * 49152;               // 49152 bf16
    float*          gsum = (float*)(whhp + 49152 + 8);                 // 2*512 (pad to 4B align)
    int*            deg    = (int*)(gsum + 2 * GG);                    // n
    int*            rowptr = deg + n;                                  // n+1
    int*            cursor = rowptr + n + 1;                           // n
    int*            col    = cursor + n;                               // e

    hipMemsetAsync(deg, 0, (size_t)n * sizeof(int), stream);
    hipMemsetAsync(gsum, 0, 2 * GG * sizeof(float), stream);

    int wave_blocks = (n * 64 + 255) / 256;
    lin0_kernel<<<wave_blocks, 256, 0, stream>>>(x, lin0_w, out_x1, hf, hbf, n);
    hist_kernel<<<(e + 255) / 256, 256, 0, stream>>>(dstp, deg, e);
    scan_kernel<<<1, 1024, 0, stream>>>(deg, rowptr, cursor, n);
    scatter_kernel<<<(e + 255) / 256, 256, 0, stream>>>(src, dstp, cursor, col, e);
    pack_whh<<<(49152 + 255) / 256, 256, 0, stream>>>(w_hh, whhp);
    pack_wf<<<(LAYERS * 49152 + 255) / 256, 256, 0, stream>>>(ggc, w_ih, Wfp);

    int gru_blocks = (n + 31) / 32;  // 3125
    for (int l = 0; l < LAYERS; ++l) {
        aggregate_kernel<<<wave_blocks, 256, 0, stream>>>((const unsigned int*)hbf, rowptr, col,
                                                          (unsigned int*)agg, n);
        gru_mfma_kernel<<<gru_blocks, 256, 0, stream>>>(agg, hbf, hf,
                                                        Wfp + (size_t)l * 49152, whhp,
                                                        b_ih, b_hh, n);
    }

    readout_kernel<<<wave_blocks, 256, 0, stream>>>(hf, l1w, l1b, l2w, l2b, batch,
                                                    out_mu, out_sg, gsum, n);
    correction_kernel<<<(n + 255) / 256, 256, 0, stream>>>(out_mu, out_sg, gsum, batch,
                                                           out_muc, n);
}

// Round 3
// 1313.805 us; speedup vs baseline: 4.9442x; 1.3657x over previous
//
#include <hip/hip_runtime.h>
#include <math.h>

#define NN 100000
#define FIN 27
#define EMB 64
#define HH 128
#define LAYERS 4
#define GG 512

typedef __attribute__((ext_vector_type(8))) short short8;
typedef __attribute__((ext_vector_type(4))) float floatx4;

__device__ __forceinline__ float sigmf(float x) { return 1.0f / (1.0f + expf(-x)); }

__device__ __forceinline__ unsigned short f2bf(float f) {
    unsigned int u = __float_as_uint(f);
    u += 0x7FFFu + ((u >> 16) & 1u);
    return (unsigned short)(u >> 16);
}

__device__ __forceinline__ float bflo(unsigned int v) { return __uint_as_float(v << 16); }
__device__ __forceinline__ float bfhi(unsigned int v) { return __uint_as_float(v & 0xFFFF0000u); }

// x1 = sigmoid(x @ lin0_w); h = pad(x1) to 128 (fp32 + bf16 mirror).
__global__ void lin0_kernel(const float* __restrict__ x, const float* __restrict__ w,
                            float* __restrict__ x1_out, float* __restrict__ hf,
                            unsigned short* __restrict__ hbf, int n) {
    int wave = (int)((blockIdx.x * blockDim.x + threadIdx.x) >> 6);
    int lane = threadIdx.x & 63;
    if (wave >= n) return;
    const float* xr = x + (size_t)wave * FIN;
    float acc = 0.0f;
#pragma unroll
    for (int k = 0; k < FIN; ++k) acc += xr[k] * w[k * EMB + lane];
    float v = sigmf(acc);
    x1_out[(size_t)wave * EMB + lane] = v;
    size_t base = (size_t)wave * HH;
    hf[base + lane] = v;
    hf[base + 64 + lane] = 0.0f;
    hbf[base + lane] = f2bf(v);
    hbf[base + 64 + lane] = 0;
}

__global__ void hist_kernel(const int* __restrict__ dst, int* __restrict__ deg, int e) {
    int i = blockIdx.x * blockDim.x + threadIdx.x;
    if (i < e) atomicAdd(&deg[dst[i]], 1);
}

__global__ void scan_kernel(const int* __restrict__ deg, int* __restrict__ rowptr,
                            int* __restrict__ cursor, int n) {
    __shared__ int part[1024];
    int t = threadIdx.x;
    int chunk = (n + 1023) / 1024;
    int lo = t * chunk;
    int hi = lo + chunk; if (hi > n) hi = n; if (lo > n) lo = n;
    int s = 0;
    for (int i = lo; i < hi; ++i) s += deg[i];
    part[t] = s;
    __syncthreads();
    for (int off = 1; off < 1024; off <<= 1) {
        int v = (t >= off) ? part[t - off] : 0;
        __syncthreads();
        part[t] += v;
        __syncthreads();
    }
    int run = (t == 0) ? 0 : part[t - 1];
    if (t == 0) rowptr[0] = 0;
    for (int i = lo; i < hi; ++i) {
        cursor[i] = run;
        run += deg[i];
        rowptr[i + 1] = run;
    }
}

__global__ void scatter_kernel(const int* __restrict__ src, const int* __restrict__ dst,
                               int* __restrict__ cursor, int* __restrict__ col, int e) {
    int i = blockIdx.x * blockDim.x + threadIdx.x;
    if (i < e) {
        int pos = atomicAdd(&cursor[dst[i]], 1);
        col[pos] = src[i];
    }
}

// Pack whh^T into MFMA B-fragment order.
__global__ void pack_whh(const float* __restrict__ w_hh, unsigned short* __restrict__ whhp) {
    int id = blockIdx.x * blockDim.x + threadIdx.x;
    if (id >= 4 * 24 * 64 * 8) return;
    int j = id & 7;
    int lane = (id >> 3) & 63;
    int ctkt = id >> 9;
    int ct = ctkt % 24;
    int kt = ctkt / 24;
    int k = kt * 32 + (lane >> 4) * 8 + j;
    int col = ct * 16 + (lane & 15);
    whhp[id] = f2bf(w_hh[col * HH + k]);
}

// Wf[l] = ggc[l] @ w_ih^T, packed in MFMA B-fragment order (bf16).
__global__ void pack_wf(const float* __restrict__ ggc, const float* __restrict__ w_ih,
                        unsigned short* __restrict__ Wfp) {
    int id = blockIdx.x * blockDim.x + threadIdx.x;
    if (id >= LAYERS * 4 * 24 * 64 * 8) return;
    int l = id / 49152;
    int rem = id % 49152;
    int j = rem & 7;
    int lane = (rem >> 3) & 63;
    int ctkt = rem >> 9;
    int ct = ctkt % 24;
    int kt = ctkt / 24;
    int k = kt * 32 + (lane >> 4) * 8 + j;
    int col = ct * 16 + (lane & 15);
    const float* gr = ggc + ((size_t)l * HH + k) * HH;
    const float* wr = w_ih + (size_t)col * HH;
    float acc = 0.0f;
#pragma unroll 8
    for (int q = 0; q < HH; ++q) acc += gr[q] * wr[q];
    Wfp[id] = f2bf(acc);
}

// agg[v] = sum over in-edges of h_bf16[src]. Wave per node; lane = 2 channels (one uint).
// Unrolled x4 with two accumulator pairs to keep multiple gathers in flight.
__global__ void aggregate_kernel(const unsigned int* __restrict__ hbf2, const int* __restrict__ rowptr,
                                 const int* __restrict__ col, unsigned int* __restrict__ agg2, int n) {
    int wave = (int)((blockIdx.x * blockDim.x + threadIdx.x) >> 6);
    int lane = threadIdx.x & 63;
    if (wave >= n) return;
    int r0 = rowptr[wave], r1 = rowptr[wave + 1];
    float a0 = 0.0f, a1 = 0.0f, b0 = 0.0f, b1 = 0.0f;
    int j = r0;
    for (; j + 3 < r1; j += 4) {
        int s0 = col[j], s1 = col[j + 1], s2 = col[j + 2], s3 = col[j + 3];
        unsigned int v0 = hbf2[(size_t)s0 * 64 + lane];
        unsigned int v1 = hbf2[(size_t)s1 * 64 + lane];
        unsigned int v2 = hbf2[(size_t)s2 * 64 + lane];
        unsigned int v3 = hbf2[(size_t)s3 * 64 + lane];
        a0 += bflo(v0); a1 += bfhi(v0);
        b0 += bflo(v1); b1 += bfhi(v1);
        a0 += bflo(v2); a1 += bfhi(v2);
        b0 += bflo(v3); b1 += bfhi(v3);
    }
    for (; j < r1; ++j) {
        unsigned int v = hbf2[(size_t)col[j] * 64 + lane];
        a0 += bflo(v); a1 += bfhi(v);
    }
    a0 += b0; a1 += b1;
    unsigned int lo = f2bf(a0);
    unsigned int hi = f2bf(a1);
    agg2[(size_t)wave * 64 + lane] = lo | (hi << 16);
}

// Fused GEMM + GRU layer. Block = 256 thr (4 waves) = 32 nodes.
__global__ void gru_mfma_kernel(const unsigned short* __restrict__ agg,
                                unsigned short* __restrict__ hbf,
                                float* __restrict__ hf,
                                const unsigned short* __restrict__ Wfp,
                                const unsigned short* __restrict__ whhp,
                                const float* __restrict__ b_ih, const float* __restrict__ b_hh,
                                int n) {
    int wave = threadIdx.x >> 6;
    int lane = threadIdx.x & 63;
    int quad = lane >> 4;
    int l15 = lane & 15;
    int M0 = blockIdx.x * 32;
    if (M0 >= n) return;

    floatx4 acc_gi[3][2][2];
    floatx4 acc_gh[3][2][2];
#pragma unroll
    for (int g = 0; g < 3; ++g)
#pragma unroll
        for (int t = 0; t < 2; ++t)
#pragma unroll
            for (int r = 0; r < 2; ++r) {
                acc_gi[g][t][r] = (floatx4)0.0f;
                acc_gh[g][t][r] = (floatx4)0.0f;
            }

    for (int kt = 0; kt < 4; ++kt) {
        int kbase = kt * 32 + quad * 8;
        short8 a_a[2], a_h[2];
#pragma unroll
        for (int r = 0; r < 2; ++r) {
            size_t arow = (size_t)(M0 + 16 * r + l15) * HH + kbase;
            a_a[r] = *(const short8*)(agg + arow);
            a_h[r] = *(const short8*)(hbf + arow);
        }
#pragma unroll
        for (int g = 0; g < 3; ++g)
#pragma unroll
            for (int t = 0; t < 2; ++t) {
                int ct = g * 8 + wave * 2 + t;
                size_t boff = ((size_t)(kt * 24 + ct) * 64 + lane) * 8;
                short8 bi = *(const short8*)(Wfp + boff);
                short8 bh = *(const short8*)(whhp + boff);
#pragma unroll
                for (int r = 0; r < 2; ++r) {
                    acc_gi[g][t][r] = __builtin_amdgcn_mfma_f32_16x16x32_bf16(
                        a_a[r], bi, acc_gi[g][t][r], 0, 0, 0);
                    acc_gh[g][t][r] = __builtin_amdgcn_mfma_f32_16x16x32_bf16(
                        a_h[r], bh, acc_gh[g][t][r], 0, 0, 0);
                }
            }
    }

    __syncthreads();  // all waves' A-reads done before any in-place h writes

#pragma unroll
    for (int t = 0; t < 2; ++t) {
        int c = wave * 32 + 16 * t + l15;
        float bir = b_ih[c], biz = b_ih[128 + c], bin_ = b_ih[256 + c];
        float bhr = b_hh[c], bhz = b_hh[128 + c], bhn = b_hh[256 + c];
#pragma unroll
        for (int r = 0; r < 2; ++r) {
#pragma unroll
            for (int j = 0; j < 4; ++j) {
                int node = M0 + 16 * r + quad * 4 + j;
                size_t idx = (size_t)node * HH + c;
                float gir = acc_gi[0][t][r][j] + bir;
                float ghr = acc_gh[0][t][r][j] + bhr;
                float giz = acc_gi[1][t][r][j] + biz;
                float ghz = acc_gh[1][t][r][j] + bhz;
                float gin = acc_gi[2][t][r][j] + bin_;
                float ghn = acc_gh[2][t][r][j] + bhn;
                float rr = sigmf(gir + ghr);
                float zz = sigmf(giz + ghz);
                float nn = tanhf(gin + rr * ghn);
                float hp = hf[idx];
                float hn = (1.0f - zz) * nn + zz * hp;
                hf[idx] = hn;
                hbf[idx] = f2bf(hn);
            }
        }
    }
}

// Per-node mu/sigma only — NO atomics.
__global__ void readout_kernel(const float* __restrict__ h, const float* __restrict__ w1,
                               const float* __restrict__ b1, const float* __restrict__ w2,
                               const float* __restrict__ b2,
                               float* __restrict__ out_mu, float* __restrict__ out_sg, int n) {
    int wave = (int)((blockIdx.x * blockDim.x + threadIdx.x) >> 6);
    int lane = threadIdx.x & 63;
    if (wave >= n) return;
    size_t base = (size_t)wave * HH;
    float xlo = fmaxf(h[base + lane], 0.0f);
    float xhi = fmaxf(h[base + 64 + lane], 0.0f);
    float a1 = xlo * w1[lane] + xhi * w1[64 + lane];
    float a2 = xlo * w2[lane] + xhi * w2[64 + lane];
#pragma unroll
    for (int off = 32; off > 0; off >>= 1) {
        a1 += __shfl_down(a1, off, 64);
        a2 += __shfl_down(a2, off, 64);
    }
    if (lane == 0) {
        float mu = a1 + b1[0];
        float x2 = a2 + b2[0];
        float sg = (x2 > 20.0f) ? x2 : log1pf(expf(x2));
        out_mu[wave] = mu;
        out_sg[wave] = sg;
    }
}

__device__ __forceinline__ int lbound(const int* __restrict__ a, int n, int v) {
    int lo = 0, hi = n;
    while (lo < hi) {
        int m = (lo + hi) >> 1;
        if (a[m] < v) lo = m + 1; else hi = m;
    }
    return lo;
}

// One block per graph: batch is sorted, binary-search the range, block-reduce
// mu_all/sigma_all, then apply the correction in the same block. Zero atomics.
__global__ void seg_correct_kernel(const float* __restrict__ out_mu, const float* __restrict__ out_sg,
                                   const int* __restrict__ batch, float* __restrict__ out_muc, int n) {
    int g = blockIdx.x;
    int lo = lbound(batch, n, g);
    int hi = lbound(batch, n, g + 1);
    float smu = 0.0f, ssg = 0.0f;
    for (int i = lo + threadIdx.x; i < hi; i += blockDim.x) {
        smu += out_mu[i];
        ssg += out_sg[i];
    }
#pragma unroll
    for (int off = 32; off > 0; off >>= 1) {
        smu += __shfl_down(smu, off, 64);
        ssg += __shfl_down(ssg, off, 64);
    }
    __shared__ float pm[4], ps[4];
    int wave = threadIdx.x >> 6;
    int lane = threadIdx.x & 63;
    if (lane == 0) { pm[wave] = smu; ps[wave] = ssg; }
    __syncthreads();
    float tot_mu = pm[0] + pm[1] + pm[2] + pm[3];
    float tot_sg = ps[0] + ps[1] + ps[2] + ps[3];
    for (int i = lo + threadIdx.x; i < hi; i += blockDim.x) {
        out_muc[i] = out_mu[i] - tot_mu * (out_sg[i] / tot_sg);
    }
}

extern "C" void kernel_launch(void* const* d_in, const int* in_sizes, int n_in,
                              void* d_out, int out_size, void* d_ws, size_t ws_size,
                              hipStream_t stream) {
    const float* x      = (const float*)d_in[0];
    const int*   ei     = (const int*)d_in[1];
    const int*   batch  = (const int*)d_in[2];
    const float* lin0_w = (const float*)d_in[3];
    const float* ggc    = (const float*)d_in[4];
    const float* w_ih   = (const float*)d_in[5];
    const float* w_hh   = (const float*)d_in[6];
    const float* b_ih   = (const float*)d_in[7];
    const float* b_hh   = (const float*)d_in[8];
    const float* l1w    = (const float*)d_in[9];
    const float* l1b    = (const float*)d_in[10];
    const float* l2w    = (const float*)d_in[11];
    const float* l2b    = (const float*)d_in[12];

    int n = in_sizes[0] / FIN;   // 100000
    int e = in_sizes[1] / 2;     // 1600000
    const int* src = ei;
    const int* dstp = ei + e;

    float* out = (float*)d_out;
    float* out_muc = out;                              // [n]
    float* out_x1  = out + n;                          // [n*64]
    float* out_sg  = out + n + (size_t)n * EMB;        // [n]
    float* out_mu  = out_sg + n;                       // [n]

    // workspace layout (all 16B aligned)
    float*          hf   = (float*)d_ws;                               // n*128 fp32
    unsigned short* hbf  = (unsigned short*)(hf + (size_t)n * HH);     // n*128 bf16
    unsigned short* agg  = hbf + (size_t)n * HH;                       // n*128 bf16
    unsigned short* Wfp  = agg + (size_t)n * HH;                       // 4*49152 bf16
    unsigned short* whhp = Wfp + (size_t)LAYERS * 49152;               // 49152 bf16
    int*            deg    = (int*)(whhp + 49152 + 8);                 // n
    int*            rowptr = deg + n;                                  // n+1
    int*            cursor = rowptr + n + 1;                           // n
    int*            col    = cursor + n;                               // e

    hipMemsetAsync(deg, 0, (size_t)n * sizeof(int), stream);

    int wave_blocks = (n * 64 + 255) / 256;
    lin0_kernel<<<wave_blocks, 256, 0, stream>>>(x, lin0_w, out_x1, hf, hbf, n);
    hist_kernel<<<(e + 255) / 256, 256, 0, stream>>>(dstp, deg, e);
    scan_kernel<<<1, 1024, 0, stream>>>(deg, rowptr, cursor, n);
    scatter_kernel<<<(e + 255) / 256, 256, 0, stream>>>(src, dstp, cursor, col, e);
    pack_whh<<<(49152 + 255) / 256, 256, 0, stream>>>(w_hh, whhp);
    pack_wf<<<(LAYERS * 49152 + 255) / 256, 256, 0, stream>>>(ggc, w_ih, Wfp);

    int gru_blocks = (n + 31) / 32;  // 3125
    for (int l = 0; l < LAYERS; ++l) {
        aggregate_kernel<<<wave_blocks, 256, 0, stream>>>((const unsigned int*)hbf, rowptr, col,
                                                          (unsigned int*)agg, n);
        gru_mfma_kernel<<<gru_blocks, 256, 0, stream>>>(agg, hbf, hf,
                                                        Wfp + (size_t)l * 49152, whhp,
                                                        b_ih, b_hh, n);
    }

    readout_kernel<<<wave_blocks, 256, 0, stream>>>(hf, l1w, l1b, l2w, l2b,
                                                    out_mu, out_sg, n);
    seg_correct_kernel<<<GG, 256, 0, stream>>>(out_mu, out_sg, batch, out_muc, n);
}

// Round 4
// 1089.339 us; speedup vs baseline: 5.9629x; 1.2061x over previous
//
#include <hip/hip_runtime.h>
#include <math.h>

#define NN 100000
#define FIN 27
#define EMB 64
#define HH 128
#define LAYERS 4
#define GG 512
#define SCAN_CHUNK 2048   // 256 threads x 8 elements

typedef __attribute__((ext_vector_type(8))) short short8;
typedef __attribute__((ext_vector_type(4))) float floatx4;

__device__ __forceinline__ float sigmf(float x) { return 1.0f / (1.0f + expf(-x)); }

__device__ __forceinline__ unsigned short f2bf(float f) {
    unsigned int u = __float_as_uint(f);
    u += 0x7FFFu + ((u >> 16) & 1u);
    return (unsigned short)(u >> 16);
}

__device__ __forceinline__ float bflo(unsigned int v) { return __uint_as_float(v << 16); }
__device__ __forceinline__ float bfhi(unsigned int v) { return __uint_as_float(v & 0xFFFF0000u); }

// x1 = sigmoid(x @ lin0_w); h = pad(x1) to 128 (fp32 + bf16 mirror).
__global__ void lin0_kernel(const float* __restrict__ x, const float* __restrict__ w,
                            float* __restrict__ x1_out, float* __restrict__ hf,
                            unsigned short* __restrict__ hbf, int n) {
    int wave = (int)((blockIdx.x * blockDim.x + threadIdx.x) >> 6);
    int lane = threadIdx.x & 63;
    if (wave >= n) return;
    const float* xr = x + (size_t)wave * FIN;
    float acc = 0.0f;
#pragma unroll
    for (int k = 0; k < FIN; ++k) acc += xr[k] * w[k * EMB + lane];
    float v = sigmf(acc);
    x1_out[(size_t)wave * EMB + lane] = v;
    size_t base = (size_t)wave * HH;
    hf[base + lane] = v;
    hf[base + 64 + lane] = 0.0f;
    hbf[base + lane] = f2bf(v);
    hbf[base + 64 + lane] = 0;
}

__global__ void hist_kernel(const int* __restrict__ dst, int* __restrict__ deg, int e) {
    int i = blockIdx.x * blockDim.x + threadIdx.x;
    if (i < e) atomicAdd(&deg[dst[i]], 1);
}

// ---- multi-block exclusive scan of deg -> rowptr/cursor ----
__global__ void scan_partial(const int* __restrict__ deg, int* __restrict__ blocksum, int n) {
    int b = blockIdx.x, t = threadIdx.x;
    int base = b * SCAN_CHUNK + t * 8;
    int s = 0;
#pragma unroll
    for (int i = 0; i < 8; ++i) {
        int idx = base + i;
        if (idx < n) s += deg[idx];
    }
#pragma unroll
    for (int off = 32; off > 0; off >>= 1) s += __shfl_down(s, off, 64);
    __shared__ int ws[4];
    if ((t & 63) == 0) ws[t >> 6] = s;
    __syncthreads();
    if (t == 0) blocksum[b] = ws[0] + ws[1] + ws[2] + ws[3];
}

// single wave: exclusive scan of nb (<=64) block sums
__global__ void scan_blocksums(const int* __restrict__ blocksum, int* __restrict__ blockoff, int nb) {
    int t = threadIdx.x;
    int own = (t < nb) ? blocksum[t] : 0;
    int v = own;
    for (int off = 1; off < 64; off <<= 1) {
        int u = __shfl_up(v, off, 64);
        if (t >= off) v += u;
    }
    if (t < nb) blockoff[t] = v - own;
}

__global__ void scan_final(const int* __restrict__ deg, const int* __restrict__ blockoff,
                           int* __restrict__ rowptr, int* __restrict__ cursor, int n) {
    int b = blockIdx.x, t = threadIdx.x;
    int base = b * SCAN_CHUNK + t * 8;
    int v[8];
    int s = 0;
#pragma unroll
    for (int i = 0; i < 8; ++i) {
        int idx = base + i;
        v[i] = (idx < n) ? deg[idx] : 0;
        s += v[i];
    }
    __shared__ int ts[256];
    ts[t] = s;
    __syncthreads();
    for (int off = 1; off < 256; off <<= 1) {
        int u = (t >= off) ? ts[t - off] : 0;
        __syncthreads();
        ts[t] += u;
        __syncthreads();
    }
    int run = blockoff[b] + ((t == 0) ? 0 : ts[t - 1]);
#pragma unroll
    for (int i = 0; i < 8; ++i) {
        int idx = base + i;
        if (idx < n) {
            rowptr[idx] = run;
            cursor[idx] = run;
            run += v[i];
        } else if (idx == n) {
            rowptr[n] = run;
        }
    }
}

__global__ void scatter_kernel(const int* __restrict__ src, const int* __restrict__ dst,
                               int* __restrict__ cursor, int* __restrict__ col, int e) {
    int i = blockIdx.x * blockDim.x + threadIdx.x;
    if (i < e) {
        int pos = atomicAdd(&cursor[dst[i]], 1);
        col[pos] = src[i];
    }
}

// Pack whh^T into MFMA B-fragment order.
__global__ void pack_whh(const float* __restrict__ w_hh, unsigned short* __restrict__ whhp) {
    int id = blockIdx.x * blockDim.x + threadIdx.x;
    if (id >= 4 * 24 * 64 * 8) return;
    int j = id & 7;
    int lane = (id >> 3) & 63;
    int ctkt = id >> 9;
    int ct = ctkt % 24;
    int kt = ctkt / 24;
    int k = kt * 32 + (lane >> 4) * 8 + j;
    int col = ct * 16 + (lane & 15);
    whhp[id] = f2bf(w_hh[col * HH + k]);
}

// Wf[l] = ggc[l] @ w_ih^T, packed in MFMA B-fragment order (bf16).
__global__ void pack_wf(const float* __restrict__ ggc, const float* __restrict__ w_ih,
                        unsigned short* __restrict__ Wfp) {
    int id = blockIdx.x * blockDim.x + threadIdx.x;
    if (id >= LAYERS * 4 * 24 * 64 * 8) return;
    int l = id / 49152;
    int rem = id % 49152;
    int j = rem & 7;
    int lane = (rem >> 3) & 63;
    int ctkt = rem >> 9;
    int ct = ctkt % 24;
    int kt = ctkt / 24;
    int k = kt * 32 + (lane >> 4) * 8 + j;
    int col = ct * 16 + (lane & 15);
    const float* gr = ggc + ((size_t)l * HH + k) * HH;
    const float* wr = w_ih + (size_t)col * HH;
    float acc = 0.0f;
#pragma unroll 8
    for (int q = 0; q < HH; ++q) acc += gr[q] * wr[q];
    Wfp[id] = f2bf(acc);
}

// agg[v] = sum over in-edges of h_bf16[src]. One wave per node; 16 lanes cover a
// 256B row via uint4, the 4 lane-groups process 4 edges concurrently.
__global__ void aggregate_kernel(const uint4* __restrict__ hbf4, const int* __restrict__ rowptr,
                                 const int* __restrict__ col, uint4* __restrict__ agg4, int n) {
    int wave = (int)((blockIdx.x * blockDim.x + threadIdx.x) >> 6);
    int lane = threadIdx.x & 63;
    if (wave >= n) return;
    int lg = lane >> 4, l16 = lane & 15;
    int r0 = rowptr[wave], r1 = rowptr[wave + 1];
    float acc[8];
#pragma unroll
    for (int k = 0; k < 8; ++k) acc[k] = 0.0f;
    for (int j = r0 + lg; j < r1; j += 4) {
        int s = col[j];
        uint4 v = hbf4[(size_t)s * 16 + l16];
        acc[0] += bflo(v.x); acc[1] += bfhi(v.x);
        acc[2] += bflo(v.y); acc[3] += bfhi(v.y);
        acc[4] += bflo(v.z); acc[5] += bfhi(v.z);
        acc[6] += bflo(v.w); acc[7] += bfhi(v.w);
    }
#pragma unroll
    for (int k = 0; k < 8; ++k) {
        acc[k] += __shfl_xor(acc[k], 32, 64);
        acc[k] += __shfl_xor(acc[k], 16, 64);
    }
    if (lg == 0) {
        uint4 o;
        o.x = (unsigned)f2bf(acc[0]) | ((unsigned)f2bf(acc[1]) << 16);
        o.y = (unsigned)f2bf(acc[2]) | ((unsigned)f2bf(acc[3]) << 16);
        o.z = (unsigned)f2bf(acc[4]) | ((unsigned)f2bf(acc[5]) << 16);
        o.w = (unsigned)f2bf(acc[6]) | ((unsigned)f2bf(acc[7]) << 16);
        agg4[(size_t)wave * 16 + l16] = o;
    }
}

// Fused GEMM + GRU layer. Block = 256 thr (4 waves) = 32 nodes.
__global__ void gru_mfma_kernel(const unsigned short* __restrict__ agg,
                                unsigned short* __restrict__ hbf,
                                float* __restrict__ hf,
                                const unsigned short* __restrict__ Wfp,
                                const unsigned short* __restrict__ whhp,
                                const float* __restrict__ b_ih, const float* __restrict__ b_hh,
                                int n) {
    int wave = threadIdx.x >> 6;
    int lane = threadIdx.x & 63;
    int quad = lane >> 4;
    int l15 = lane & 15;
    int M0 = blockIdx.x * 32;
    if (M0 >= n) return;

    floatx4 acc_gi[3][2][2];
    floatx4 acc_gh[3][2][2];
#pragma unroll
    for (int g = 0; g < 3; ++g)
#pragma unroll
        for (int t = 0; t < 2; ++t)
#pragma unroll
            for (int r = 0; r < 2; ++r) {
                acc_gi[g][t][r] = (floatx4)0.0f;
                acc_gh[g][t][r] = (floatx4)0.0f;
            }

    for (int kt = 0; kt < 4; ++kt) {
        int kbase = kt * 32 + quad * 8;
        short8 a_a[2], a_h[2];
#pragma unroll
        for (int r = 0; r < 2; ++r) {
            size_t arow = (size_t)(M0 + 16 * r + l15) * HH + kbase;
            a_a[r] = *(const short8*)(agg + arow);
            a_h[r] = *(const short8*)(hbf + arow);
        }
#pragma unroll
        for (int g = 0; g < 3; ++g)
#pragma unroll
            for (int t = 0; t < 2; ++t) {
                int ct = g * 8 + wave * 2 + t;
                size_t boff = ((size_t)(kt * 24 + ct) * 64 + lane) * 8;
                short8 bi = *(const short8*)(Wfp + boff);
                short8 bh = *(const short8*)(whhp + boff);
#pragma unroll
                for (int r = 0; r < 2; ++r) {
                    acc_gi[g][t][r] = __builtin_amdgcn_mfma_f32_16x16x32_bf16(
                        a_a[r], bi, acc_gi[g][t][r], 0, 0, 0);
                    acc_gh[g][t][r] = __builtin_amdgcn_mfma_f32_16x16x32_bf16(
                        a_h[r], bh, acc_gh[g][t][r], 0, 0, 0);
                }
            }
    }

    __syncthreads();  // all waves' A-reads done before any in-place h writes

#pragma unroll
    for (int t = 0; t < 2; ++t) {
        int c = wave * 32 + 16 * t + l15;
        float bir = b_ih[c], biz = b_ih[128 + c], bin_ = b_ih[256 + c];
        float bhr = b_hh[c], bhz = b_hh[128 + c], bhn = b_hh[256 + c];
#pragma unroll
        for (int r = 0; r < 2; ++r) {
#pragma unroll
            for (int j = 0; j < 4; ++j) {
                int node = M0 + 16 * r + quad * 4 + j;
                size_t idx = (size_t)node * HH + c;
                float gir = acc_gi[0][t][r][j] + bir;
                float ghr = acc_gh[0][t][r][j] + bhr;
                float giz = acc_gi[1][t][r][j] + biz;
                float ghz = acc_gh[1][t][r][j] + bhz;
                float gin = acc_gi[2][t][r][j] + bin_;
                float ghn = acc_gh[2][t][r][j] + bhn;
                float rr = sigmf(gir + ghr);
                float zz = sigmf(giz + ghz);
                float nn = tanhf(gin + rr * ghn);
                float hp = hf[idx];
                float hn = (1.0f - zz) * nn + zz * hp;
                hf[idx] = hn;
                hbf[idx] = f2bf(hn);
            }
        }
    }
}

// Per-node mu/sigma only — NO atomics.
__global__ void readout_kernel(const float* __restrict__ h, const float* __restrict__ w1,
                               const float* __restrict__ b1, const float* __restrict__ w2,
                               const float* __restrict__ b2,
                               float* __restrict__ out_mu, float* __restrict__ out_sg, int n) {
    int wave = (int)((blockIdx.x * blockDim.x + threadIdx.x) >> 6);
    int lane = threadIdx.x & 63;
    if (wave >= n) return;
    size_t base = (size_t)wave * HH;
    float xlo = fmaxf(h[base + lane], 0.0f);
    float xhi = fmaxf(h[base + 64 + lane], 0.0f);
    float a1 = xlo * w1[lane] + xhi * w1[64 + lane];
    float a2 = xlo * w2[lane] + xhi * w2[64 + lane];
#pragma unroll
    for (int off = 32; off > 0; off >>= 1) {
        a1 += __shfl_down(a1, off, 64);
        a2 += __shfl_down(a2, off, 64);
    }
    if (lane == 0) {
        float mu = a1 + b1[0];
        float x2 = a2 + b2[0];
        float sg = (x2 > 20.0f) ? x2 : log1pf(expf(x2));
        out_mu[wave] = mu;
        out_sg[wave] = sg;
    }
}

__device__ __forceinline__ int lbound(const int* __restrict__ a, int n, int v) {
    int lo = 0, hi = n;
    while (lo < hi) {
        int m = (lo + hi) >> 1;
        if (a[m] < v) lo = m + 1; else hi = m;
    }
    return lo;
}

// One block per graph: block-reduce mu_all/sigma_all, apply correction. Zero atomics.
__global__ void seg_correct_kernel(const float* __restrict__ out_mu, const float* __restrict__ out_sg,
                                   const int* __restrict__ batch, float* __restrict__ out_muc, int n) {
    int g = blockIdx.x;
    int lo = lbound(batch, n, g);
    int hi = lbound(batch, n, g + 1);
    float smu = 0.0f, ssg = 0.0f;
    for (int i = lo + threadIdx.x; i < hi; i += blockDim.x) {
        smu += out_mu[i];
        ssg += out_sg[i];
    }
#pragma unroll
    for (int off = 32; off > 0; off >>= 1) {
        smu += __shfl_down(smu, off, 64);
        ssg += __shfl_down(ssg, off, 64);
    }
    __shared__ float pm[4], ps[4];
    int wave = threadIdx.x >> 6;
    int lane = threadIdx.x & 63;
    if (lane == 0) { pm[wave] = smu; ps[wave] = ssg; }
    __syncthreads();
    float tot_mu = pm[0] + pm[1] + pm[2] + pm[3];
    float tot_sg = ps[0] + ps[1] + ps[2] + ps[3];
    for (int i = lo + threadIdx.x; i < hi; i += blockDim.x) {
        out_muc[i] = out_mu[i] - tot_mu * (out_sg[i] / tot_sg);
    }
}

extern "C" void kernel_launch(void* const* d_in, const int* in_sizes, int n_in,
                              void* d_out, int out_size, void* d_ws, size_t ws_size,
                              hipStream_t stream) {
    const float* x      = (const float*)d_in[0];
    const int*   ei     = (const int*)d_in[1];
    const int*   batch  = (const int*)d_in[2];
    const float* lin0_w = (const float*)d_in[3];
    const float* ggc    = (const float*)d_in[4];
    const float* w_ih   = (const float*)d_in[5];
    const float* w_hh   = (const float*)d_in[6];
    const float* b_ih   = (const float*)d_in[7];
    const float* b_hh   = (const float*)d_in[8];
    const float* l1w    = (const float*)d_in[9];
    const float* l1b    = (const float*)d_in[10];
    const float* l2w    = (const float*)d_in[11];
    const float* l2b    = (const float*)d_in[12];

    int n = in_sizes[0] / FIN;   // 100000
    int e = in_sizes[1] / 2;     // 1600000
    const int* src = ei;
    const int* dstp = ei + e;

    float* out = (float*)d_out;
    float* out_muc = out;                              // [n]
    float* out_x1  = out + n;                          // [n*64]
    float* out_sg  = out + n + (size_t)n * EMB;        // [n]
    float* out_mu  = out_sg + n;                       // [n]

    // workspace layout (all 16B aligned)
    float*          hf   = (float*)d_ws;                               // n*128 fp32
    unsigned short* hbf  = (unsigned short*)(hf + (size_t)n * HH);     // n*128 bf16
    unsigned short* agg  = hbf + (size_t)n * HH;                       // n*128 bf16
    unsigned short* Wfp  = agg + (size_t)n * HH;                       // 4*49152 bf16
    unsigned short* whhp = Wfp + (size_t)LAYERS * 49152;               // 49152 bf16
    int*            deg      = (int*)(whhp + 49152 + 8);               // n
    int*            rowptr   = deg + n;                                // n+1
    int*            cursor   = rowptr + n + 1;                         // n
    int*            blocksum = cursor + n;                             // 64
    int*            blockoff = blocksum + 64;                          // 64
    int*            col      = blockoff + 64;                          // e

    hipMemsetAsync(deg, 0, (size_t)n * sizeof(int), stream);

    int wave_blocks = (n * 64 + 255) / 256;
    lin0_kernel<<<wave_blocks, 256, 0, stream>>>(x, lin0_w, out_x1, hf, hbf, n);
    hist_kernel<<<(e + 255) / 256, 256, 0, stream>>>(dstp, deg, e);

    int nb = (n + SCAN_CHUNK) / SCAN_CHUNK;  // covers idx==n too; 49 for n=100000
    scan_partial<<<nb, 256, 0, stream>>>(deg, blocksum, n);
    scan_blocksums<<<1, 64, 0, stream>>>(blocksum, blockoff, nb);
    scan_final<<<nb, 256, 0, stream>>>(deg, blockoff, rowptr, cursor, n);

    scatter_kernel<<<(e + 255) / 256, 256, 0, stream>>>(src, dstp, cursor, col, e);
    pack_whh<<<(49152 + 255) / 256, 256, 0, stream>>>(w_hh, whhp);
    pack_wf<<<(LAYERS * 49152 + 255) / 256, 256, 0, stream>>>(ggc, w_ih, Wfp);

    int gru_blocks = (n + 31) / 32;  // 3125
    for (int l = 0; l < LAYERS; ++l) {
        aggregate_kernel<<<wave_blocks, 256, 0, stream>>>((const uint4*)hbf, rowptr, col,
                                                          (uint4*)agg, n);
        gru_mfma_kernel<<<gru_blocks, 256, 0, stream>>>(agg, hbf, hf,
                                                        Wfp + (size_t)l * 49152, whhp,
                                                        b_ih, b_hh, n);
    }

    readout_kernel<<<wave_blocks, 256, 0, stream>>>(hf, l1w, l1b, l2w, l2b,
                                                    out_mu, out_sg, n);
    seg_correct_kernel<<<GG, 256, 0, stream>>>(out_mu, out_sg, batch, out_muc, n);
}

// Round 5
// 970.172 us; speedup vs baseline: 6.6954x; 1.1228x over previous
//
#include <hip/hip_runtime.h>
#include <math.h>

#define NN 100000
#define FIN 27
#define EMB 64
#define HH 128
#define LAYERS 4
#define GG 512
#define SCAN_CHUNK 2048   // 256 threads x 8 elements
#define SPAN 512          // nodes per bucket
#define SPANSHIFT 9
#define MAXNB 256

typedef __attribute__((ext_vector_type(8))) short short8;
typedef __attribute__((ext_vector_type(4))) float floatx4;

__device__ __forceinline__ float sigmf(float x) { return 1.0f / (1.0f + expf(-x)); }

__device__ __forceinline__ unsigned short f2bf(float f) {
    unsigned int u = __float_as_uint(f);
    u += 0x7FFFu + ((u >> 16) & 1u);
    return (unsigned short)(u >> 16);
}

__device__ __forceinline__ float bflo(unsigned int v) { return __uint_as_float(v << 16); }
__device__ __forceinline__ float bfhi(unsigned int v) { return __uint_as_float(v & 0xFFFF0000u); }

// x1 = sigmoid(x @ lin0_w); h = pad(x1) to 128 (fp32 + bf16 mirror).
__global__ void lin0_kernel(const float* __restrict__ x, const float* __restrict__ w,
                            float* __restrict__ x1_out, float* __restrict__ hf,
                            unsigned short* __restrict__ hbf, int n) {
    int wave = (int)((blockIdx.x * blockDim.x + threadIdx.x) >> 6);
    int lane = threadIdx.x & 63;
    if (wave >= n) return;
    const float* xr = x + (size_t)wave * FIN;
    float acc = 0.0f;
#pragma unroll
    for (int k = 0; k < FIN; ++k) acc += xr[k] * w[k * EMB + lane];
    float v = sigmf(acc);
    x1_out[(size_t)wave * EMB + lane] = v;
    size_t base = (size_t)wave * HH;
    hf[base + lane] = v;
    hf[base + 64 + lane] = 0.0f;
    hbf[base + lane] = f2bf(v);
    hbf[base + 64 + lane] = 0;
}

// ---- bucketed CSR build ----
__global__ void bucket_hist(const int* __restrict__ dst, int* __restrict__ bucket_cnt,
                            int e, int nb) {
    __shared__ int lh[MAXNB];
    int t = threadIdx.x;  // 1024
    for (int i = t; i < MAXNB; i += 1024) lh[i] = 0;
    __syncthreads();
    int base = blockIdx.x * 16384;
#pragma unroll
    for (int i = 0; i < 16; ++i) {
        int eid = base + i * 1024 + t;
        if (eid < e) atomicAdd(&lh[dst[eid] >> SPANSHIFT], 1);
    }
    __syncthreads();
    for (int i = t; i < nb; i += 1024) {
        int c = lh[i];
        if (c) atomicAdd(&bucket_cnt[i], c);
    }
}

__global__ void bucket_scan(const int* __restrict__ bucket_cnt, int* __restrict__ bucket_off,
                            int* __restrict__ bucket_cursor, int nb) {
    __shared__ int ts[256];
    int t = threadIdx.x;
    int v = (t < nb) ? bucket_cnt[t] : 0;
    ts[t] = v;
    __syncthreads();
    for (int off = 1; off < 256; off <<= 1) {
        int u = (t >= off) ? ts[t - off] : 0;
        __syncthreads();
        ts[t] += u;
        __syncthreads();
    }
    int excl = ts[t] - v;
    if (t < nb) { bucket_off[t] = excl; bucket_cursor[t] = excl; }
    if (t == 255) bucket_off[nb] = ts[255];
}

__global__ void bucket_scatter(const int* __restrict__ src, const int* __restrict__ dst,
                               int* __restrict__ bucket_cursor, uint2* __restrict__ ebuf, int e) {
    __shared__ int lh[MAXNB];
    __shared__ int gb[MAXNB];
    int t = threadIdx.x;  // 1024
    for (int i = t; i < MAXNB; i += 1024) lh[i] = 0;
    __syncthreads();
    int base = blockIdx.x * 16384;
    int lidx[16], sv[16], dv[16];
#pragma unroll
    for (int i = 0; i < 16; ++i) {
        int eid = base + i * 1024 + t;
        if (eid < e) {
            sv[i] = src[eid];
            dv[i] = dst[eid];
            lidx[i] = atomicAdd(&lh[dv[i] >> SPANSHIFT], 1);
        } else lidx[i] = -1;
    }
    __syncthreads();
    for (int i = t; i < MAXNB; i += 1024) {
        int c = lh[i];
        gb[i] = c ? atomicAdd(&bucket_cursor[i], c) : 0;
    }
    __syncthreads();
#pragma unroll
    for (int i = 0; i < 16; ++i) {
        if (lidx[i] >= 0) {
            int b = dv[i] >> SPANSHIFT;
            ebuf[gb[b] + lidx[i]] = make_uint2((unsigned)sv[i], (unsigned)dv[i]);
        }
    }
}

// Per-node degree via per-bucket LDS histogram (replaces random global atomics).
__global__ void deg_from_buckets(const uint2* __restrict__ ebuf, const int* __restrict__ bucket_off,
                                 int* __restrict__ deg, int n) {
    __shared__ int ld[SPAN];
    int b = blockIdx.x, t = threadIdx.x;  // 256
    ld[t] = 0; ld[t + 256] = 0;
    __syncthreads();
    int lo = bucket_off[b], hi = bucket_off[b + 1];
    int nodebase = b << SPANSHIFT;
    for (int j = lo + t; j < hi; j += 256)
        atomicAdd(&ld[(int)ebuf[j].y - nodebase], 1);
    __syncthreads();
    int i0 = nodebase + t, i1 = nodebase + 256 + t;
    if (i0 < n) deg[i0] = ld[t];
    if (i1 < n) deg[i1] = ld[t + 256];
}

// ---- multi-block exclusive scan of deg -> rowptr ----
__global__ void scan_partial(const int* __restrict__ deg, int* __restrict__ blocksum, int n) {
    int b = blockIdx.x, t = threadIdx.x;
    int base = b * SCAN_CHUNK + t * 8;
    int s = 0;
#pragma unroll
    for (int i = 0; i < 8; ++i) {
        int idx = base + i;
        if (idx < n) s += deg[idx];
    }
#pragma unroll
    for (int off = 32; off > 0; off >>= 1) s += __shfl_down(s, off, 64);
    __shared__ int ws[4];
    if ((t & 63) == 0) ws[t >> 6] = s;
    __syncthreads();
    if (t == 0) blocksum[b] = ws[0] + ws[1] + ws[2] + ws[3];
}

__global__ void scan_blocksums(const int* __restrict__ blocksum, int* __restrict__ blockoff, int nb) {
    int t = threadIdx.x;
    int own = (t < nb) ? blocksum[t] : 0;
    int v = own;
    for (int off = 1; off < 64; off <<= 1) {
        int u = __shfl_up(v, off, 64);
        if (t >= off) v += u;
    }
    if (t < nb) blockoff[t] = v - own;
}

__global__ void scan_final(const int* __restrict__ deg, const int* __restrict__ blockoff,
                           int* __restrict__ rowptr, int n) {
    int b = blockIdx.x, t = threadIdx.x;
    int base = b * SCAN_CHUNK + t * 8;
    int v[8];
    int s = 0;
#pragma unroll
    for (int i = 0; i < 8; ++i) {
        int idx = base + i;
        v[i] = (idx < n) ? deg[idx] : 0;
        s += v[i];
    }
    __shared__ int ts[256];
    ts[t] = s;
    __syncthreads();
    for (int off = 1; off < 256; off <<= 1) {
        int u = (t >= off) ? ts[t - off] : 0;
        __syncthreads();
        ts[t] += u;
        __syncthreads();
    }
    int run = blockoff[b] + ((t == 0) ? 0 : ts[t - 1]);
#pragma unroll
    for (int i = 0; i < 8; ++i) {
        int idx = base + i;
        if (idx < n) {
            rowptr[idx] = run;
            run += v[i];
        } else if (idx == n) {
            rowptr[n] = run;
        }
    }
}

// Place edges into CSR col with LDS cursors; writes confined to ~32KB/bucket.
__global__ void place_kernel(const uint2* __restrict__ ebuf, const int* __restrict__ bucket_off,
                             const int* __restrict__ rowptr, int* __restrict__ col, int n) {
    __shared__ int cur[SPAN];
    int b = blockIdx.x, t = threadIdx.x;  // 256
    int nodebase = b << SPANSHIFT;
    int i0 = nodebase + t, i1 = nodebase + 256 + t;
    cur[t] = (i0 < n) ? rowptr[i0] : 0;
    cur[t + 256] = (i1 < n) ? rowptr[i1] : 0;
    __syncthreads();
    int lo = bucket_off[b], hi = bucket_off[b + 1];
    for (int j = lo + t; j < hi; j += 256) {
        uint2 ed = ebuf[j];
        int pos = atomicAdd(&cur[(int)ed.y - nodebase], 1);
        col[pos] = (int)ed.x;
    }
}

// Pack whh^T into MFMA B-fragment order.
__global__ void pack_whh(const float* __restrict__ w_hh, unsigned short* __restrict__ whhp) {
    int id = blockIdx.x * blockDim.x + threadIdx.x;
    if (id >= 4 * 24 * 64 * 8) return;
    int j = id & 7;
    int lane = (id >> 3) & 63;
    int ctkt = id >> 9;
    int ct = ctkt % 24;
    int kt = ctkt / 24;
    int k = kt * 32 + (lane >> 4) * 8 + j;
    int col = ct * 16 + (lane & 15);
    whhp[id] = f2bf(w_hh[col * HH + k]);
}

// Wf[l] = ggc[l] @ w_ih^T, packed in MFMA B-fragment order (bf16).
__global__ void pack_wf(const float* __restrict__ ggc, const float* __restrict__ w_ih,
                        unsigned short* __restrict__ Wfp) {
    int id = blockIdx.x * blockDim.x + threadIdx.x;
    if (id >= LAYERS * 4 * 24 * 64 * 8) return;
    int l = id / 49152;
    int rem = id % 49152;
    int j = rem & 7;
    int lane = (rem >> 3) & 63;
    int ctkt = rem >> 9;
    int ct = ctkt % 24;
    int kt = ctkt / 24;
    int k = kt * 32 + (lane >> 4) * 8 + j;
    int col = ct * 16 + (lane & 15);
    const float* gr = ggc + ((size_t)l * HH + k) * HH;
    const float* wr = w_ih + (size_t)col * HH;
    float acc = 0.0f;
#pragma unroll 8
    for (int q = 0; q < HH; ++q) acc += gr[q] * wr[q];
    Wfp[id] = f2bf(acc);
}

// agg[v] = sum over in-edges of h_bf16[src]. One wave per node; 16 lanes cover a
// 256B row via uint4, the 4 lane-groups process 4 edges concurrently.
__global__ void aggregate_kernel(const uint4* __restrict__ hbf4, const int* __restrict__ rowptr,
                                 const int* __restrict__ col, uint4* __restrict__ agg4, int n) {
    int wave = (int)((blockIdx.x * blockDim.x + threadIdx.x) >> 6);
    int lane = threadIdx.x & 63;
    if (wave >= n) return;
    int lg = lane >> 4, l16 = lane & 15;
    int r0 = rowptr[wave], r1 = rowptr[wave + 1];
    float acc[8];
#pragma unroll
    for (int k = 0; k < 8; ++k) acc[k] = 0.0f;
    for (int j = r0 + lg; j < r1; j += 4) {
        int s = col[j];
        uint4 v = hbf4[(size_t)s * 16 + l16];
        acc[0] += bflo(v.x); acc[1] += bfhi(v.x);
        acc[2] += bflo(v.y); acc[3] += bfhi(v.y);
        acc[4] += bflo(v.z); acc[5] += bfhi(v.z);
        acc[6] += bflo(v.w); acc[7] += bfhi(v.w);
    }
#pragma unroll
    for (int k = 0; k < 8; ++k) {
        acc[k] += __shfl_xor(acc[k], 32, 64);
        acc[k] += __shfl_xor(acc[k], 16, 64);
    }
    if (lg == 0) {
        uint4 o;
        o.x = (unsigned)f2bf(acc[0]) | ((unsigned)f2bf(acc[1]) << 16);
        o.y = (unsigned)f2bf(acc[2]) | ((unsigned)f2bf(acc[3]) << 16);
        o.z = (unsigned)f2bf(acc[4]) | ((unsigned)f2bf(acc[5]) << 16);
        o.w = (unsigned)f2bf(acc[6]) | ((unsigned)f2bf(acc[7]) << 16);
        agg4[(size_t)wave * 16 + l16] = o;
    }
}

// Fused GEMM + GRU layer. Block = 256 thr (4 waves) = 32 nodes.
__global__ void gru_mfma_kernel(const unsigned short* __restrict__ agg,
                                unsigned short* __restrict__ hbf,
                                float* __restrict__ hf,
                                const unsigned short* __restrict__ Wfp,
                                const unsigned short* __restrict__ whhp,
                                const float* __restrict__ b_ih, const float* __restrict__ b_hh,
                                int n) {
    int wave = threadIdx.x >> 6;
    int lane = threadIdx.x & 63;
    int quad = lane >> 4;
    int l15 = lane & 15;
    int M0 = blockIdx.x * 32;
    if (M0 >= n) return;

    floatx4 acc_gi[3][2][2];
    floatx4 acc_gh[3][2][2];
#pragma unroll
    for (int g = 0; g < 3; ++g)
#pragma unroll
        for (int t = 0; t < 2; ++t)
#pragma unroll
            for (int r = 0; r < 2; ++r) {
                acc_gi[g][t][r] = (floatx4)0.0f;
                acc_gh[g][t][r] = (floatx4)0.0f;
            }

    for (int kt = 0; kt < 4; ++kt) {
        int kbase = kt * 32 + quad * 8;
        short8 a_a[2], a_h[2];
#pragma unroll
        for (int r = 0; r < 2; ++r) {
            size_t arow = (size_t)(M0 + 16 * r + l15) * HH + kbase;
            a_a[r] = *(const short8*)(agg + arow);
            a_h[r] = *(const short8*)(hbf + arow);
        }
#pragma unroll
        for (int g = 0; g < 3; ++g)
#pragma unroll
            for (int t = 0; t < 2; ++t) {
                int ct = g * 8 + wave * 2 + t;
                size_t boff = ((size_t)(kt * 24 + ct) * 64 + lane) * 8;
                short8 bi = *(const short8*)(Wfp + boff);
                short8 bh = *(const short8*)(whhp + boff);
#pragma unroll
                for (int r = 0; r < 2; ++r) {
                    acc_gi[g][t][r] = __builtin_amdgcn_mfma_f32_16x16x32_bf16(
                        a_a[r], bi, acc_gi[g][t][r], 0, 0, 0);
                    acc_gh[g][t][r] = __builtin_amdgcn_mfma_f32_16x16x32_bf16(
                        a_h[r], bh, acc_gh[g][t][r], 0, 0, 0);
                }
            }
    }

    __syncthreads();  // all waves' A-reads done before any in-place h writes

#pragma unroll
    for (int t = 0; t < 2; ++t) {
        int c = wave * 32 + 16 * t + l15;
        float bir = b_ih[c], biz = b_ih[128 + c], bin_ = b_ih[256 + c];
        float bhr = b_hh[c], bhz = b_hh[128 + c], bhn = b_hh[256 + c];
#pragma unroll
        for (int r = 0; r < 2; ++r) {
#pragma unroll
            for (int j = 0; j < 4; ++j) {
                int node = M0 + 16 * r + quad * 4 + j;
                size_t idx = (size_t)node * HH + c;
                float gir = acc_gi[0][t][r][j] + bir;
                float ghr = acc_gh[0][t][r][j] + bhr;
                float giz = acc_gi[1][t][r][j] + biz;
                float ghz = acc_gh[1][t][r][j] + bhz;
                float gin = acc_gi[2][t][r][j] + bin_;
                float ghn = acc_gh[2][t][r][j] + bhn;
                float rr = sigmf(gir + ghr);
                float zz = sigmf(giz + ghz);
                float nn = tanhf(gin + rr * ghn);
                float hp = hf[idx];
                float hn = (1.0f - zz) * nn + zz * hp;
                hf[idx] = hn;
                hbf[idx] = f2bf(hn);
            }
        }
    }
}

// Per-node mu/sigma only — NO atomics.
__global__ void readout_kernel(const float* __restrict__ h, const float* __restrict__ w1,
                               const float* __restrict__ b1, const float* __restrict__ w2,
                               const float* __restrict__ b2,
                               float* __restrict__ out_mu, float* __restrict__ out_sg, int n) {
    int wave = (int)((blockIdx.x * blockDim.x + threadIdx.x) >> 6);
    int lane = threadIdx.x & 63;
    if (wave >= n) return;
    size_t base = (size_t)wave * HH;
    float xlo = fmaxf(h[base + lane], 0.0f);
    float xhi = fmaxf(h[base + 64 + lane], 0.0f);
    float a1 = xlo * w1[lane] + xhi * w1[64 + lane];
    float a2 = xlo * w2[lane] + xhi * w2[64 + lane];
#pragma unroll
    for (int off = 32; off > 0; off >>= 1) {
        a1 += __shfl_down(a1, off, 64);
        a2 += __shfl_down(a2, off, 64);
    }
    if (lane == 0) {
        float mu = a1 + b1[0];
        float x2 = a2 + b2[0];
        float sg = (x2 > 20.0f) ? x2 : log1pf(expf(x2));
        out_mu[wave] = mu;
        out_sg[wave] = sg;
    }
}

__device__ __forceinline__ int lbound(const int* __restrict__ a, int n, int v) {
    int lo = 0, hi = n;
    while (lo < hi) {
        int m = (lo + hi) >> 1;
        if (a[m] < v) lo = m + 1; else hi = m;
    }
    return lo;
}

// One block per graph: block-reduce mu_all/sigma_all, apply correction. Zero atomics.
__global__ void seg_correct_kernel(const float* __restrict__ out_mu, const float* __restrict__ out_sg,
                                   const int* __restrict__ batch, float* __restrict__ out_muc, int n) {
    int g = blockIdx.x;
    int lo = lbound(batch, n, g);
    int hi = lbound(batch, n, g + 1);
    float smu = 0.0f, ssg = 0.0f;
    for (int i = lo + threadIdx.x; i < hi; i += blockDim.x) {
        smu += out_mu[i];
        ssg += out_sg[i];
    }
#pragma unroll
    for (int off = 32; off > 0; off >>= 1) {
        smu += __shfl_down(smu, off, 64);
        ssg += __shfl_down(ssg, off, 64);
    }
    __shared__ float pm[4], ps[4];
    int wave = threadIdx.x >> 6;
    int lane = threadIdx.x & 63;
    if (lane == 0) { pm[wave] = smu; ps[wave] = ssg; }
    __syncthreads();
    float tot_mu = pm[0] + pm[1] + pm[2] + pm[3];
    float tot_sg = ps[0] + ps[1] + ps[2] + ps[3];
    for (int i = lo + threadIdx.x; i < hi; i += blockDim.x) {
        out_muc[i] = out_mu[i] - tot_mu * (out_sg[i] / tot_sg);
    }
}

extern "C" void kernel_launch(void* const* d_in, const int* in_sizes, int n_in,
                              void* d_out, int out_size, void* d_ws, size_t ws_size,
                              hipStream_t stream) {
    const float* x      = (const float*)d_in[0];
    const int*   ei     = (const int*)d_in[1];
    const int*   batch  = (const int*)d_in[2];
    const float* lin0_w = (const float*)d_in[3];
    const float* ggc    = (const float*)d_in[4];
    const float* w_ih   = (const float*)d_in[5];
    const float* w_hh   = (const float*)d_in[6];
    const float* b_ih   = (const float*)d_in[7];
    const float* b_hh   = (const float*)d_in[8];
    const float* l1w    = (const float*)d_in[9];
    const float* l1b    = (const float*)d_in[10];
    const float* l2w    = (const float*)d_in[11];
    const float* l2b    = (const float*)d_in[12];

    int n = in_sizes[0] / FIN;   // 100000
    int e = in_sizes[1] / 2;     // 1600000
    const int* src = ei;
    const int* dstp = ei + e;

    float* out = (float*)d_out;
    float* out_muc = out;                              // [n]
    float* out_x1  = out + n;                          // [n*64]
    float* out_sg  = out + n + (size_t)n * EMB;        // [n]
    float* out_mu  = out_sg + n;                       // [n]

    // workspace layout (all 16B aligned)
    float*          hf   = (float*)d_ws;                               // n*128 fp32
    unsigned short* hbf  = (unsigned short*)(hf + (size_t)n * HH);     // n*128 bf16
    unsigned short* agg  = hbf + (size_t)n * HH;                       // n*128 bf16
    unsigned short* Wfp  = agg + (size_t)n * HH;                       // 4*49152 bf16
    unsigned short* whhp = Wfp + (size_t)LAYERS * 49152;               // 49152 bf16
    int*            deg      = (int*)(whhp + 49152 + 8);               // n
    int*            rowptr   = deg + n;                                // n+1
    int*            blocksum = rowptr + n + 1;                         // 64
    int*            blockoff = blocksum + 64;                          // 64
    int*            bucket_cnt    = blockoff + 64;                     // MAXNB
    int*            bucket_off    = bucket_cnt + MAXNB;                // MAXNB+1
    int*            bucket_cursor = bucket_off + MAXNB + 1;            // MAXNB
    int*            col      = bucket_cursor + MAXNB;                  // e
    uint2*          ebuf     = (uint2*)agg;   // 12.8MB, aliases agg (CSR build precedes aggregates)

    int nbuck = (n + SPAN - 1) >> SPANSHIFT;   // 196
    hipMemsetAsync(bucket_cnt, 0, MAXNB * sizeof(int), stream);

    int wave_blocks = (n * 64 + 255) / 256;
    lin0_kernel<<<wave_blocks, 256, 0, stream>>>(x, lin0_w, out_x1, hf, hbf, n);

    int eb = (e + 16383) / 16384;  // 98
    bucket_hist<<<eb, 1024, 0, stream>>>(dstp, bucket_cnt, e, nbuck);
    bucket_scan<<<1, 256, 0, stream>>>(bucket_cnt, bucket_off, bucket_cursor, nbuck);
    bucket_scatter<<<eb, 1024, 0, stream>>>(src, dstp, bucket_cursor, ebuf, e);
    deg_from_buckets<<<nbuck, 256, 0, stream>>>(ebuf, bucket_off, deg, n);

    int nb = (n + SCAN_CHUNK) / SCAN_CHUNK;  // covers idx==n too
    scan_partial<<<nb, 256, 0, stream>>>(deg, blocksum, n);
    scan_blocksums<<<1, 64, 0, stream>>>(blocksum, blockoff, nb);
    scan_final<<<nb, 256, 0, stream>>>(deg, blockoff, rowptr, n);

    place_kernel<<<nbuck, 256, 0, stream>>>(ebuf, bucket_off, rowptr, col, n);

    pack_whh<<<(49152 + 255) / 256, 256, 0, stream>>>(w_hh, whhp);
    pack_wf<<<(LAYERS * 49152 + 255) / 256, 256, 0, stream>>>(ggc, w_ih, Wfp);

    int gru_blocks = (n + 31) / 32;  // 3125
    for (int l = 0; l < LAYERS; ++l) {
        aggregate_kernel<<<wave_blocks, 256, 0, stream>>>((const uint4*)hbf, rowptr, col,
                                                          (uint4*)agg, n);
        gru_mfma_kernel<<<gru_blocks, 256, 0, stream>>>(agg, hbf, hf,
                                                        Wfp + (size_t)l * 49152, whhp,
                                                        b_ih, b_hh, n);
    }

    readout_kernel<<<wave_blocks, 256, 0, stream>>>(hf, l1w, l1b, l2w, l2b,
                                                    out_mu, out_sg, n);
    seg_correct_kernel<<<GG, 256, 0, stream>>>(out_mu, out_sg, batch, out_muc, n);
}